// Round 8
// baseline (69.495 us; speedup 1.0000x reference)
//
#include <hip/hip_runtime.h>
#include <hip/hip_bf16.h>

#define BATCH     32768
#define NPAIR     64
#define NBLK      128          /* route blocks: BATCH/256 */

typedef __bf16 bf16x8 __attribute__((ext_vector_type(8)));
typedef float  f32x4  __attribute__((ext_vector_type(4)));
static_assert(sizeof(bf16x8) == 16, "bf16x8 must be 16B");

// ---- workspace byte offsets ----
#define WS_CNT      0
#define WS_BASE     256
#define WS_BH       1024
#define WS_OFF      (WS_BH + NBLK*NPAIR*4)
#define WS_PAIR     (WS_OFF + NBLK*NPAIR*4)
#define WS_ROWLIST  (WS_PAIR + BATCH*4)
#define WS_WT00     (WS_ROWLIST + BATCH*4)
#define WS_WT01     (WS_WT00 + 131072*2)
#define WS_WT1P     (WS_WT01 + 262144*2)
#define WS_WT1A     (WS_WT1P + 131072*2)
#define WS_WT1O     (WS_WT1A + 393216*2)
#define WS_HO       (WS_WT1O + 32768*2)     /* B x 128 bf16 = 8 MB */

__device__ __forceinline__ unsigned short f2bf(float x) {
  __bf16 h = (__bf16)x;
  return __builtin_bit_cast(unsigned short, h);
}

#define KEEP(x) asm volatile("" : "+v"(x))

// Merged: blocks 0..239 transpose weights fp32->bf16 [m][o][i]; blocks 240..367 route.
__global__ __launch_bounds__(256) void k_combo(const float* __restrict__ w00,
                                               const float* __restrict__ w01,
                                               const float* __restrict__ w1p,
                                               const float* __restrict__ w1a,
                                               const float* __restrict__ w1o,
                                               const float* __restrict__ inp,
                                               char* __restrict__ ws) {
  __shared__ unsigned short lds[64 * 72];
  int bid = blockIdx.x;
  if (bid >= 240) {
    int* h = (int*)lds;
    int rbid = bid - 240;
    int t = threadIdx.x;
    if (t < NPAIR) h[t] = 0;
    __syncthreads();
    int r = rbid * 256 + t;
    const float* q = inp + (size_t)r * 144 + 128;
    float4 u0 = *(const float4*)(q + 0);
    float4 u1 = *(const float4*)(q + 4);
    float4 v0 = *(const float4*)(q + 8);
    float4 v1 = *(const float4*)(q + 12);
    int a0 = 0;
    if (u0.y > 0.5f) a0 = 1; if (u0.z > 0.5f) a0 = 2; if (u0.w > 0.5f) a0 = 3;
    if (u1.x > 0.5f) a0 = 4; if (u1.y > 0.5f) a0 = 5; if (u1.z > 0.5f) a0 = 6; if (u1.w > 0.5f) a0 = 7;
    int a1 = 0;
    if (v0.y > 0.5f) a1 = 1; if (v0.z > 0.5f) a1 = 2; if (v0.w > 0.5f) a1 = 3;
    if (v1.x > 0.5f) a1 = 4; if (v1.y > 0.5f) a1 = 5; if (v1.z > 0.5f) a1 = 6; if (v1.w > 0.5f) a1 = 7;
    int p = a0 * 8 + a1;
    ((int*)(ws + WS_PAIR))[r] = p;
    atomicAdd(&h[p], 1);
    __syncthreads();
    if (t < NPAIR) ((int*)(ws + WS_BH))[rbid * NPAIR + t] = h[t];
    return;
  }
  const float* src; unsigned short* dst; int I, O, lt;
  if (bid < 32)       { src = w00; dst = (unsigned short*)(ws + WS_WT00); I = 64;  O = 256; lt = bid; }
  else if (bid < 96)  { src = w01; dst = (unsigned short*)(ws + WS_WT01); I = 256; O = 128; lt = bid - 32; }
  else if (bid < 128) { src = w1p; dst = (unsigned short*)(ws + WS_WT1P); I = 64;  O = 256; lt = bid - 96; }
  else if (bid < 224) { src = w1a; dst = (unsigned short*)(ws + WS_WT1A); I = 384; O = 128; lt = bid - 128; }
  else                { src = w1o; dst = (unsigned short*)(ws + WS_WT1O); I = 128; O = 32;  lt = bid - 224; }
  int tI = I >> 6;
  int tO = (O + 63) >> 6;
  int m   = lt / (tI * tO);
  int rem = lt % (tI * tO);
  int ib = rem / tO, ob = rem % tO;
  int tx = threadIdx.x & 63, ty = threadIdx.x >> 6;
  const float* s = src + (size_t)m * I * O;
  #pragma unroll 4
  for (int s4 = 0; s4 < 16; ++s4) {
    int li = s4 * 4 + ty;
    int o  = ob * 64 + tx;
    float v = (o < O) ? s[(size_t)(ib * 64 + li) * O + o] : 0.f;
    lds[li * 72 + tx] = f2bf(v);
  }
  __syncthreads();
  unsigned short* d = dst + (size_t)m * O * I;
  #pragma unroll 4
  for (int s4 = 0; s4 < 16; ++s4) {
    int lo = s4 * 4 + ty;
    int o  = ob * 64 + lo;
    if (o < O) d[(size_t)o * I + ib * 64 + tx] = lds[tx * 72 + lo];
  }
}

// Scan: 1 block x 1024 threads. Outputs cnt[p], base[p], per-(block,pair) off.
__global__ __launch_bounds__(1024) void k_scan(const int* __restrict__ bh,
                                               int* __restrict__ cnt,
                                               int* __restrict__ base,
                                               int* __restrict__ off) {
  __shared__ int part[16][NPAIR];
  __shared__ int bs64[NPAIR];
  int tid = threadIdx.x;
  int p = tid & 63, c = tid >> 6;
  int loc[8]; int s = 0;
  #pragma unroll
  for (int i = 0; i < 8; ++i) { loc[i] = s; s += bh[(c * 8 + i) * NPAIR + p]; }
  part[c][p] = s;
  __syncthreads();
  if (tid < 64) {
    int run = 0;
    #pragma unroll
    for (int c2 = 0; c2 < 16; ++c2) { int v = part[c2][p]; part[c2][p] = run; run += v; }
    cnt[p] = run;
    int x = run;
    #pragma unroll
    for (int d = 1; d < 64; d <<= 1) { int y = __shfl_up(x, d); if (p >= d) x += y; }
    int bs = x - run;
    base[p] = bs;
    bs64[p] = bs;
  }
  __syncthreads();
  int add = part[c][p] + bs64[p];
  #pragma unroll
  for (int i = 0; i < 8; ++i) off[(c * 8 + i) * NPAIR + p] = loc[i] + add;
}

// Scatter: LDS-local rank + precomputed global offset. NO global atomics.
__global__ __launch_bounds__(256) void k_scatter(const int* __restrict__ pairArr,
                                                 const int* __restrict__ off,
                                                 int* __restrict__ rowlist) {
  __shared__ int h[NPAIR];
  int t = threadIdx.x;
  if (t < NPAIR) h[t] = 0;
  __syncthreads();
  int r = blockIdx.x * 256 + threadIdx.x;
  int p = pairArr[r];
  int rank = atomicAdd(&h[p], 1);
  rowlist[off[blockIdx.x * NPAIR + p] + rank] = r;
}

// Kernel A: e0-branch (L00 -> L01 -> HO in ws, rowlist order).
// Grid 512 = 8 e0-groups x 64 slices; 8 waves; LDS 16KB (H1); weight regs = 48/lane.
__global__ __launch_bounds__(512, 4) void k_fwdA(
    const float* __restrict__ inp,
    const float* __restrict__ b00, const float* __restrict__ b01,
    char* __restrict__ ws)
{
  __shared__ unsigned short H1m[8192];   // 32x256 bf16, stride 512B, swizzled

  int e0    = blockIdx.x >> 6;
  int slice = blockIdx.x & 63;
  const int* baseArr = (const int*)(ws + WS_BASE);
  int rbA  = baseArr[e0 * 8];
  int cnt0 = ((e0 == 7) ? BATCH : baseArr[e0 * 8 + 8]) - rbA;
  int ntiles = (cnt0 + 31) >> 5;
  if (slice >= ntiles || cnt0 <= 0) return;
  const int* rlbase = (const int*)(ws + WS_ROWLIST) + rbA;
  const unsigned short* wt00 = (const unsigned short*)(ws + WS_WT00);
  const unsigned short* wt01 = (const unsigned short*)(ws + WS_WT01);
  unsigned short* hoG = (unsigned short*)(ws + WS_HO);

  int lane = threadIdx.x & 63;
  int w    = threadIdx.x >> 6;
  int ln   = lane & 15;
  int lq   = lane >> 4;
  int kcol = lq * 8;

  // loop-invariant weights: 48 VGPRs/lane -> fits under 128 cap, truly resident
  bf16x8 w00f[2][2];
  #pragma unroll
  for (int nt = 0; nt < 2; ++nt) {
    int n = w * 32 + nt * 16 + ln;
    #pragma unroll
    for (int kc = 0; kc < 2; ++kc)
      w00f[nt][kc] = *(const bf16x8*)(wt00 + ((size_t)(e0 * 256 + n) * 64 + kc * 32 + kcol));
  }
  bf16x8 wc[8];
  #pragma unroll
  for (int kc = 0; kc < 8; ++kc)
    wc[kc] = *(const bf16x8*)(wt01 + ((size_t)(e0 * 128 + w * 16 + ln) * 256 + kc * 32 + kcol));
  #pragma unroll
  for (int nt = 0; nt < 2; ++nt)
    #pragma unroll
    for (int kc = 0; kc < 2; ++kc) KEEP(w00f[nt][kc]);
  #pragma unroll
  for (int kc = 0; kc < 8; ++kc) KEEP(wc[kc]);

  float bias00[2];
  #pragma unroll
  for (int nt = 0; nt < 2; ++nt) bias00[nt] = b00[e0 * 256 + w * 32 + nt * 16 + ln];
  float bias01 = b01[e0 * 128 + w * 16 + ln];

  const f32x4 z4 = {0.f, 0.f, 0.f, 0.f};

  for (int t = slice; t < ntiles; t += 64) {
    int nr = min(32, cnt0 - t * 32);
    const int* rl = rlbase + t * 32;

    int rowA[2];
    #pragma unroll
    for (int mt = 0; mt < 2; ++mt) {
      int rloc = mt * 16 + ln;
      rowA[mt] = (rloc < nr) ? rl[rloc] : -1;
    }
    bf16x8 axf[2][2];  // feat0 only
    #pragma unroll
    for (int mt = 0; mt < 2; ++mt) {
      #pragma unroll
      for (int kc = 0; kc < 2; ++kc) {
        bf16x8 a;
        int rg = rowA[mt];
        if (rg >= 0) {
          const float* q = inp + (size_t)rg * 144 + kc * 32 + kcol;
          float4 u = *(const float4*)(q);
          float4 v = *(const float4*)(q + 4);
          a[0] = (__bf16)u.x; a[1] = (__bf16)u.y; a[2] = (__bf16)u.z; a[3] = (__bf16)u.w;
          a[4] = (__bf16)v.x; a[5] = (__bf16)v.y; a[6] = (__bf16)v.z; a[7] = (__bf16)v.w;
        } else {
          #pragma unroll
          for (int j = 0; j < 8; ++j) a[j] = (__bf16)0.f;
        }
        axf[mt][kc] = a;
      }
    }

    // P1: L00 -> H1
    #pragma unroll
    for (int nt = 0; nt < 2; ++nt) {
      int n = w * 32 + nt * 16 + ln;
      f32x4 acc[2] = {z4, z4};
      #pragma unroll
      for (int kc = 0; kc < 2; ++kc)
        #pragma unroll
        for (int mt = 0; mt < 2; ++mt)
          acc[mt] = __builtin_amdgcn_mfma_f32_16x16x32_bf16(axf[mt][kc], w00f[nt][kc], acc[mt], 0, 0, 0);
      #pragma unroll
      for (int mt = 0; mt < 2; ++mt)
        #pragma unroll
        for (int r = 0; r < 4; ++r) {
          int row = mt * 16 + lq * 4 + r;
          float v = fmaxf(acc[mt][r] + bias00[nt], 0.f);
          H1m[(row * 512 + ((n << 1) ^ ((row & 7) << 4))) >> 1] = f2bf(v);
        }
    }
    __syncthreads();

    // P2: L01 -> HO (global, rowlist order, coalesced)
    {
      f32x4 accc[2] = {z4, z4};
      #pragma unroll
      for (int kc = 0; kc < 8; ++kc) {
        bf16x8 afr[2];
        #pragma unroll
        for (int mt = 0; mt < 2; ++mt) {
          int row = mt * 16 + ln;
          afr[mt] = *(const bf16x8*)&H1m[(row * 512 + (((kc * 32 + kcol) << 1) ^ ((row & 7) << 4))) >> 1];
        }
        #pragma unroll
        for (int mt = 0; mt < 2; ++mt)
          accc[mt] = __builtin_amdgcn_mfma_f32_16x16x32_bf16(afr[mt], wc[kc], accc[mt], 0, 0, 0);
      }
      int n = w * 16 + ln;
      #pragma unroll
      for (int mt = 0; mt < 2; ++mt)
        #pragma unroll
        for (int r = 0; r < 4; ++r) {
          int row = mt * 16 + lq * 4 + r;
          if (row < nr) {
            float v = fmaxf(accc[mt][r] + bias01, 0.f);
            hoG[(size_t)(rbA + t * 32 + row) * 128 + n] = f2bf(v);
          }
        }
    }
    __syncthreads();
  }
}

// Kernel B: e1-branch (L1p -> L1a([HO|G]) -> L1o -> out).
// Grid 256 = 64 pairs x 4 slices; 8 waves; LDS 120KB: W1a 96KB (XOR-swizzled,
// staged once) + G 16KB + G2 8KB. W1p/W1o in regs (32/lane). HO prefetched.
__global__ __launch_bounds__(512, 2) void k_fwdB(
    const float* __restrict__ inp,
    const float* __restrict__ b1p, const float* __restrict__ b1a,
    const float* __restrict__ b1o,
    char* __restrict__ ws, float* __restrict__ out)
{
  __shared__ char smem[122880];
  unsigned short* G  = (unsigned short*)(smem + 98304);   // 32x256 s512
  unsigned short* G2 = (unsigned short*)(smem + 114688);  // 32x128 s256

  int p     = blockIdx.x >> 2;
  int slice = blockIdx.x & 3;
  int e1 = p & 7;
  int cnt  = ((const int*)(ws + WS_CNT))[p];
  int base = ((const int*)(ws + WS_BASE))[p];
  int ntiles = (cnt + 31) >> 5;
  if (slice >= ntiles || cnt <= 0) return;
  const int* rlbase = (const int*)(ws + WS_ROWLIST) + base;
  const unsigned short* wt1p = (const unsigned short*)(ws + WS_WT1P);
  const unsigned short* wt1o = (const unsigned short*)(ws + WS_WT1O);
  const unsigned short* hoG  = (const unsigned short*)(ws + WS_HO);

  int lane = threadIdx.x & 63;
  int w    = threadIdx.x >> 6;
  int ln   = lane & 15;
  int lq   = lane >> 4;
  int kcol = lq * 8;

  // stage W1a[e1] (96KB) into LDS, XOR-swizzled per 768B row: d = g ^ ((o&7)<<4)
  {
    const unsigned short* src = (const unsigned short*)(ws + WS_WT1A) + (size_t)e1 * 49152;
    for (int c = threadIdx.x; c < 6144; c += 512) {
      bf16x8 v = *(const bf16x8*)(src + c * 8);
      int g = c << 4;
      int o = c / 48;                 // row (o-index), 48 chunks per 768B row
      *(bf16x8*)(smem + (g ^ ((o & 7) << 4))) = v;
    }
  }

  bf16x8 w1pf[2][2];
  #pragma unroll
  for (int nt = 0; nt < 2; ++nt) {
    int n = w * 32 + nt * 16 + ln;
    #pragma unroll
    for (int kc = 0; kc < 2; ++kc)
      w1pf[nt][kc] = *(const bf16x8*)(wt1p + ((size_t)(e1 * 256 + n) * 64 + kc * 32 + kcol));
  }
  bf16x8 wo[4];
  if (w < 4) {
    #pragma unroll
    for (int kc = 0; kc < 4; ++kc)
      wo[kc] = *(const bf16x8*)(wt1o + ((size_t)(e1 * 32 + (w >> 1) * 16 + ln) * 128 + kc * 32 + kcol));
  }
  #pragma unroll
  for (int nt = 0; nt < 2; ++nt)
    #pragma unroll
    for (int kc = 0; kc < 2; ++kc) KEEP(w1pf[nt][kc]);
  if (w < 4) {
    #pragma unroll
    for (int kc = 0; kc < 4; ++kc) KEEP(wo[kc]);
  }

  float bias1p[2];
  #pragma unroll
  for (int nt = 0; nt < 2; ++nt) bias1p[nt] = b1p[e1 * 256 + w * 32 + nt * 16 + ln];
  float bias1a = b1a[e1 * 128 + w * 16 + ln];
  float bias1o = (w < 4) ? b1o[e1 * 32 + (w >> 1) * 16 + ln] : 0.f;

  const f32x4 z4 = {0.f, 0.f, 0.f, 0.f};
  __syncthreads();  // W1a staged

  for (int t = slice; t < ntiles; t += 4) {
    int nr = min(32, cnt - t * 32);
    const int* rl = rlbase + t * 32;
    int posb = base + t * 32;

    int rowA[2];
    #pragma unroll
    for (int mt = 0; mt < 2; ++mt) {
      int rloc = mt * 16 + ln;
      rowA[mt] = (rloc < nr) ? rl[rloc] : -1;
    }
    bf16x8 axf[2][2];  // feat1
    #pragma unroll
    for (int mt = 0; mt < 2; ++mt) {
      #pragma unroll
      for (int kc = 0; kc < 2; ++kc) {
        bf16x8 a;
        int rg = rowA[mt];
        if (rg >= 0) {
          const float* q = inp + (size_t)rg * 144 + 64 + kc * 32 + kcol;
          float4 u = *(const float4*)(q);
          float4 v = *(const float4*)(q + 4);
          a[0] = (__bf16)u.x; a[1] = (__bf16)u.y; a[2] = (__bf16)u.z; a[3] = (__bf16)u.w;
          a[4] = (__bf16)v.x; a[5] = (__bf16)v.y; a[6] = (__bf16)v.z; a[7] = (__bf16)v.w;
        } else {
          #pragma unroll
          for (int j = 0; j < 8; ++j) a[j] = (__bf16)0.f;
        }
        axf[mt][kc] = a;
      }
    }

    // prefetch HO fragments (hidden under L1p)
    bf16x8 hof[2][4];
    #pragma unroll
    for (int mt = 0; mt < 2; ++mt)
      #pragma unroll
      for (int kc = 0; kc < 4; ++kc)
        hof[mt][kc] = *(const bf16x8*)(hoG + (size_t)(posb + mt * 16 + ln) * 128 + kc * 32 + kcol);
    #pragma unroll
    for (int mt = 0; mt < 2; ++mt)
      #pragma unroll
      for (int kc = 0; kc < 4; ++kc) KEEP(hof[mt][kc]);

    // P-L1p: feat1 @ W1p -> G
    #pragma unroll
    for (int nt = 0; nt < 2; ++nt) {
      int n = w * 32 + nt * 16 + ln;
      f32x4 acc[2] = {z4, z4};
      #pragma unroll
      for (int kc = 0; kc < 2; ++kc)
        #pragma unroll
        for (int mt = 0; mt < 2; ++mt)
          acc[mt] = __builtin_amdgcn_mfma_f32_16x16x32_bf16(axf[mt][kc], w1pf[nt][kc], acc[mt], 0, 0, 0);
      #pragma unroll
      for (int mt = 0; mt < 2; ++mt)
        #pragma unroll
        for (int r = 0; r < 4; ++r) {
          int row = mt * 16 + lq * 4 + r;
          float v = fmaxf(acc[mt][r] + bias1p[nt], 0.f);
          G[(row * 512 + ((n << 1) ^ ((row & 7) << 4))) >> 1] = f2bf(v);
        }
    }
    __syncthreads();

    // P-L1a: [HO(k<128) | G(k>=128)] @ W1a(LDS) -> G2
    {
      int n = w * 16 + ln;
      f32x4 acc1a[2] = {z4, z4};
      #pragma unroll
      for (int kc = 0; kc < 4; ++kc) {
        int wb = (n * 768 + ((kc * 32 + kcol) << 1)) ^ ((n & 7) << 4);
        bf16x8 bfr = *(const bf16x8*)(smem + wb);
        #pragma unroll
        for (int mt = 0; mt < 2; ++mt)
          acc1a[mt] = __builtin_amdgcn_mfma_f32_16x16x32_bf16(hof[mt][kc], bfr, acc1a[mt], 0, 0, 0);
      }
      #pragma unroll
      for (int kc = 4; kc < 12; ++kc) {
        int kk = kc - 4;
        int wb = (n * 768 + ((kc * 32 + kcol) << 1)) ^ ((n & 7) << 4);
        bf16x8 bfr = *(const bf16x8*)(smem + wb);
        bf16x8 afr[2];
        #pragma unroll
        for (int mt = 0; mt < 2; ++mt) {
          int row = mt * 16 + ln;
          afr[mt] = *(const bf16x8*)&G[(row * 512 + (((kk * 32 + kcol) << 1) ^ ((row & 7) << 4))) >> 1];
        }
        #pragma unroll
        for (int mt = 0; mt < 2; ++mt)
          acc1a[mt] = __builtin_amdgcn_mfma_f32_16x16x32_bf16(afr[mt], bfr, acc1a[mt], 0, 0, 0);
      }
      #pragma unroll
      for (int mt = 0; mt < 2; ++mt)
        #pragma unroll
        for (int r = 0; r < 4; ++r) {
          int row = mt * 16 + lq * 4 + r;
          float v = fmaxf(acc1a[mt][r] + bias1a, 0.f);
          G2[(row * 256 + ((n << 1) ^ ((row & 7) << 4))) >> 1] = f2bf(v);
        }
    }
    __syncthreads();

    // P-L1o (waves 0..3): G2 @ W1o -> out
    if (w < 4) {
      int mt = w & 1;
      int n  = (w >> 1) * 16 + ln;
      f32x4 acc = z4;
      #pragma unroll
      for (int kc = 0; kc < 4; ++kc) {
        int row = mt * 16 + ln;
        bf16x8 afr = *(const bf16x8*)&G2[(row * 256 + (((kc * 32 + kcol) << 1) ^ ((row & 7) << 4))) >> 1];
        acc = __builtin_amdgcn_mfma_f32_16x16x32_bf16(afr, wo[kc], acc, 0, 0, 0);
      }
      #pragma unroll
      for (int r = 0; r < 4; ++r) {
        int row = mt * 16 + lq * 4 + r;
        if (row < nr) {
          int rg = rl[row];
          out[(size_t)rg * 32 + n] = acc[r] + bias1o;
        }
      }
    }
    __syncthreads();  // before next tile's G rewrite
  }
}

extern "C" void kernel_launch(void* const* d_in, const int* in_sizes, int n_in,
                              void* d_out, int out_size, void* d_ws, size_t ws_size,
                              hipStream_t stream) {
  const float* inp = (const float*)d_in[0];
  const float* w00 = (const float*)d_in[1];
  const float* b00 = (const float*)d_in[2];
  const float* w01 = (const float*)d_in[3];
  const float* b01 = (const float*)d_in[4];
  const float* w1p = (const float*)d_in[5];
  const float* b1p = (const float*)d_in[6];
  const float* w1a = (const float*)d_in[7];
  const float* b1a = (const float*)d_in[8];
  const float* w1o = (const float*)d_in[9];
  const float* b1o = (const float*)d_in[10];
  char*  ws  = (char*)d_ws;
  float* out = (float*)d_out;

  k_combo<<<368, 256, 0, stream>>>(w00, w01, w1p, w1a, w1o, inp, ws);
  k_scan<<<1, 1024, 0, stream>>>((const int*)(ws + WS_BH), (int*)(ws + WS_CNT),
                                 (int*)(ws + WS_BASE), (int*)(ws + WS_OFF));
  k_scatter<<<NBLK, 256, 0, stream>>>((const int*)(ws + WS_PAIR),
                                      (const int*)(ws + WS_OFF),
                                      (int*)(ws + WS_ROWLIST));
  k_fwdA<<<512, 512, 0, stream>>>(inp, b00, b01, ws);
  k_fwdB<<<256, 512, 0, stream>>>(inp, b1p, b1a, b1o, ws, out);
}